// Round 9
// baseline (53.010 us; speedup 1.0000x reference)
//
#include <hip/hip_runtime.h>

#define TOKENS 16384
#define KDIM   2048
#define NEXP   64
#define TOPK   6
#define NSTEPS (KDIM / 32)        // 64 global K-steps
#define BM     64                 // tokens per block
#define XSB    (BM * 32)          // floats per x buffer (2048 = 8 KB)

typedef short short8 __attribute__((ext_vector_type(8)));   // 8 bf16 = 4 VGPR
typedef float f32x4  __attribute__((ext_vector_type(4)));

// Exact 3-way truncation split: f == bf(h) + bf(l) + bf(l2) + eps, |eps| <= 2^-24 |f|.
__device__ __forceinline__ void split3(float f, short& h, short& l, short& l2) {
  const unsigned u = __builtin_bit_cast(unsigned, f);
  h = (short)(u >> 16);
  const float r1 = f - __builtin_bit_cast(float, u & 0xffff0000u);
  const unsigned u1 = __builtin_bit_cast(unsigned, r1);
  l = (short)(u1 >> 16);
  const float r2 = r1 - __builtin_bit_cast(float, u1 & 0xffff0000u);
  l2 = (short)(__builtin_bit_cast(unsigned, r2) >> 16);
}

__device__ __forceinline__ void g2l16(const void* g, void* l) {
  __builtin_amdgcn_global_load_lds(
      (const __attribute__((address_space(1))) unsigned*)g,
      (__attribute__((address_space(3))) unsigned*)l, 16, 0, 0);
}

// Kernel 0: pack W into MFMA-B-fragment order, 3-term bf16 split.
// w*[s][nt][lane][j] = term of W[s*32 + (lane>>4)*8 + j][nt*16 + (lane&15)]
__global__ __launch_bounds__(256)
void moe_wpack(const float* __restrict__ wg, short* __restrict__ wh,
               short* __restrict__ wl, short* __restrict__ wl2) {
  const int tid = blockIdx.x * 256 + threadIdx.x;  // 0..16383 = (s, nt, lane)
  const int l  = tid & 63;
  const int nt = (tid >> 6) & 3;
  const int s  = tid >> 8;
  short8 a, b, c;
#pragma unroll
  for (int j = 0; j < 8; ++j) {
    const int k = s * 32 + (l >> 4) * 8 + j;
    const int n = nt * 16 + (l & 15);
    short xh, xl, xl2;
    split3(wg[(size_t)k * NEXP + n], xh, xl, xl2);
    a[j] = xh; b[j] = xl; c[j] = xl2;
  }
  *(short8*)(wh  + (size_t)tid * 8) = a;
  *(short8*)(wl  + (size_t)tid * 8) = b;
  *(short8*)(wl2 + (size_t)tid * 8) = c;
}

// Kernel 1: split-K MFMA partial GEMM (6-term bf16 split). Grid (256, ns) ->
// 4 blocks/CU = 16 waves/CU. Wave wid owns expert tile nt=wid (16 experts) x
// ALL 64 tokens (4 row-groups): the 4 waves load DISJOINT w fragments ->
// block w traffic 12 KB/iter (was 48), w:x VMEM balance fixed. Pipeline:
// [3 w-loads] -> [stage x(c+1), 2 DMA] -> s_waitcnt vmcnt(5) (retires only
// the 2 oldest = DMA(c)) -> RAW s_barrier (no vmcnt(0) drain) -> compute.
__global__ __launch_bounds__(256, 4)
void moe_mfma_ks(const float* __restrict__ x, const short* __restrict__ wh,
                 const short* __restrict__ wl, const short* __restrict__ wl2,
                 float* __restrict__ part, int Kc) {
  __shared__ float xs[3 * XSB];   // 24 KB, triple-buffered

  const int t    = threadIdx.x;
  const int lane = t & 63;
  const int wid  = t >> 6;        // wave's expert tile: experts wid*16..+15
  const int row0 = blockIdx.x * BM;
  const int k0   = blockIdx.y * Kc;
  const int nch  = Kc >> 5;
  const int s0   = k0 >> 5;       // first global K-step index

  auto stage = [&](int b, int c) {
    // 512 granules (16B): G = (tok, slot); src granule = slot ^ (tok&7)
#pragma unroll
    for (int j = 0; j < 2; ++j) {
      const int G = j * 256 + t;
      const int tok = G >> 3, slot = G & 7;
      g2l16(x + (size_t)(row0 + tok) * KDIM + k0 + c * 32 + ((slot ^ (tok & 7)) << 2),
            xs + (size_t)b * XSB + (size_t)G * 4);
    }
  };

  f32x4 accB[4] = {};   // hh term, one per row-group (magnitude ~1)
  f32x4 accS[4] = {};   // correction terms (magnitude ~2^-8)
  const int r15 = lane & 15;
  const int kb  = lane >> 4;      // my k-group of 8
  const int sw  = r15 & 7;        // swizzle key: row-group independent

  const short8* __restrict__ whv  = (const short8*)wh;
  const short8* __restrict__ wlv  = (const short8*)wl;
  const short8* __restrict__ wl2v = (const short8*)wl2;

  stage(0, 0);

  int bc = 0;                                // buffer holding chunk c
  for (int c = 0; c < nch; ++c) {
    // 1) w fragments for MY expert tile only (3 loads, disjoint across waves)
    short8 bh, bl, bl2;
    {
      const int fi = (s0 + c) * 256 + wid * 64 + lane;
      bh  = whv[fi];
      bl  = wlv[fi];
      bl2 = wl2v[fi];
    }
    __builtin_amdgcn_sched_barrier(0);

    // 2) stage chunk c+1, then retire only DMA(c) (oldest 2 in the queue)
    const int bn = (bc == 2) ? 0 : bc + 1;
    if (c + 1 < nch) {
      stage(bn, c + 1);
      __builtin_amdgcn_sched_barrier(0);
      asm volatile("s_waitcnt vmcnt(5)" ::: "memory");   // 3 w + 2 new DMA remain
    } else {
      asm volatile("s_waitcnt vmcnt(3)" ::: "memory");   // 3 w remain
    }
    __builtin_amdgcn_sched_barrier(0);
    __builtin_amdgcn_s_barrier();       // RAW barrier: no vmcnt(0) drain
    __builtin_amdgcn_sched_barrier(0);

    // 3) compute step c from buf bc: 4 row-groups x my 16 experts
#pragma unroll
    for (int rg = 0; rg < 4; ++rg) {
      const float* xrow = xs + (size_t)bc * XSB + (rg * 16 + r15) * 32;
      const float4 xa = *(const float4*)(xrow + (((kb * 2)     ^ sw) << 2));
      const float4 xb = *(const float4*)(xrow + (((kb * 2 + 1) ^ sw) << 2));
      short8 ah, al, al2;
#pragma unroll
      for (int e = 0; e < 4; ++e) {
        short h0, l0, m0, h1, l1, m1;
        split3(((const float*)&xa)[e], h0, l0, m0);
        split3(((const float*)&xb)[e], h1, l1, m1);
        ah[e] = h0; al[e] = l0; al2[e] = m0;
        ah[e + 4] = h1; al[e + 4] = l1; al2[e + 4] = m1;
      }
      accB[rg] = __builtin_amdgcn_mfma_f32_16x16x32_bf16(ah,  bh,  accB[rg], 0, 0, 0);
      accS[rg] = __builtin_amdgcn_mfma_f32_16x16x32_bf16(al,  bh,  accS[rg], 0, 0, 0);
      accS[rg] = __builtin_amdgcn_mfma_f32_16x16x32_bf16(ah,  bl,  accS[rg], 0, 0, 0);
      accS[rg] = __builtin_amdgcn_mfma_f32_16x16x32_bf16(al,  bl,  accS[rg], 0, 0, 0);
      accS[rg] = __builtin_amdgcn_mfma_f32_16x16x32_bf16(ah,  bl2, accS[rg], 0, 0, 0);
      accS[rg] = __builtin_amdgcn_mfma_f32_16x16x32_bf16(al2, bh,  accS[rg], 0, 0, 0);
    }
    bc = bn;
  }

  // ---- write f32 partials. D: col=lane&15 (expert in my tile),
  // row=(lane>>4)*4+reg (token within row-group).
  float* pb = part + (size_t)blockIdx.y * TOKENS * NEXP;
#pragma unroll
  for (int rg = 0; rg < 4; ++rg)
#pragma unroll
    for (int r = 0; r < 4; ++r)
      pb[(size_t)(row0 + rg * 16 + kb * 4 + r) * NEXP + wid * 16 + r15] =
          accB[rg][r] + accS[rg][r];
}

// Kernel 2: 16 lanes per token, 4 experts/lane (float4 loads).
// Butterfly reductions within 16-lane groups; 6 argmax rounds with jax
// tie-break (equal score -> lower index). out: indices then scores.
__global__ __launch_bounds__(256)
void moe_softmax_topk(const float* __restrict__ part, float* __restrict__ out, int ns) {
  const int lane = threadIdx.x & 63;
  const int wid  = threadIdx.x >> 6;
  const int sub  = lane & 15;
  const int tok  = blockIdx.x * 16 + wid * 4 + (lane >> 4);

  float v[4] = {0.f, 0.f, 0.f, 0.f};
  for (int ks = 0; ks < ns; ++ks) {
    const float4 p = *(const float4*)(part + ((size_t)ks * TOKENS + tok) * NEXP + sub * 4);
    v[0] += p.x; v[1] += p.y; v[2] += p.z; v[3] += p.w;
  }

  float m = fmaxf(fmaxf(v[0], v[1]), fmaxf(v[2], v[3]));
#pragma unroll
  for (int off = 1; off < 16; off <<= 1) m = fmaxf(m, __shfl_xor(m, off));
  float p0 = expf(v[0] - m), p1 = expf(v[1] - m), p2 = expf(v[2] - m), p3 = expf(v[3] - m);
  float s = p0 + p1 + p2 + p3;
#pragma unroll
  for (int off = 1; off < 16; off <<= 1) s += __shfl_xor(s, off);
  v[0] = p0 / s; v[1] = p1 / s; v[2] = p2 / s; v[3] = p3 / s;

  float resv = 0.f; int resi = 0;
#pragma unroll
  for (int rr = 0; rr < TOPK; ++rr) {
    float bv = v[0]; int bi = sub * 4;
#pragma unroll
    for (int j = 1; j < 4; ++j)
      if (v[j] > bv) { bv = v[j]; bi = sub * 4 + j; }   // strict > : lowest idx on tie
#pragma unroll
    for (int off = 1; off < 16; off <<= 1) {
      const float ov = __shfl_xor(bv, off);
      const int   oi = __shfl_xor(bi, off);
      if (ov > bv || (ov == bv && oi < bi)) { bv = ov; bi = oi; }
    }
    if (sub == rr) { resv = bv; resi = bi; }
    if ((bi >> 2) == sub) v[bi & 3] = -1.f;   // scores > 0, sentinel safe
  }

  if (sub < TOPK) {
    out[(size_t)tok * TOPK + sub] = (float)resi;
    out[(size_t)TOKENS * TOPK + (size_t)tok * TOPK + sub] = resv;
  }
}

extern "C" void kernel_launch(void* const* d_in, const int* in_sizes, int n_in,
                              void* d_out, int out_size, void* d_ws, size_t ws_size,
                              hipStream_t stream) {
  const float* x  = (const float*)d_in[0];
  const float* wg = (const float*)d_in[1];
  float* out = (float*)d_out;

  short* wh  = (short*)d_ws;                        // 3 x 131072 shorts = 768 KB
  short* wl  = wh + (size_t)NSTEPS * 4 * 64 * 8;
  short* wl2 = wl + (size_t)NSTEPS * 4 * 64 * 8;
  const size_t wbytes = (size_t)3 * NSTEPS * 4 * 64 * 8 * sizeof(short);
  float* part = (float*)((char*)d_ws + wbytes);

  int ns = 4;
  while (ns > 1 && wbytes + (size_t)ns * TOKENS * NEXP * sizeof(float) > ws_size) ns >>= 1;
  const int Kc = KDIM / ns;

  moe_wpack<<<dim3(64), dim3(256), 0, stream>>>(wg, wh, wl, wl2);
  moe_mfma_ks<<<dim3(TOKENS / BM, ns), dim3(256), 0, stream>>>(x, wh, wl, wl2, part, Kc);
  moe_softmax_topk<<<dim3(TOKENS / 16), dim3(256), 0, stream>>>(part, out, ns);
}